// Round 1
// baseline (192.804 us; speedup 1.0000x reference)
//
#include <hip/hip_runtime.h>
#include <stdint.h>
#include <math.h>

// Problem constants (fixed by the reference: B=256, N=16384).
constexpr int BATCH  = 256;
constexpr int NATOM  = 16384;
constexpr int TPB    = 256;
constexpr int APT    = 4;                  // atoms per inner step (float4/int4 granule)
constexpr int NQ     = 16;                 // reduced quantities per batch

// Pass 1 geometry: fewer blocks, more atoms/thread to amortize the
// 96-shuffle reduction tree (was 4 atoms/thread -> 24 shuffles/atom;
// now 16 atoms/thread -> 6 shuffles/atom).
constexpr int C1     = 4;                  // pass-1 blocks per batch
constexpr int ITERS  = 4;                  // inner iterations of the 4-atom body
constexpr int ABLK1  = NATOM / C1;         // 4096 atoms per pass-1 block

// Pass 3 geometry (pure streaming; keep high block count).
constexpr int C3     = 16;

typedef float f32x4 __attribute__((ext_vector_type(4)));
typedef int   i32x4 __attribute__((ext_vector_type(4)));

// ---------------------------------------------------------------------------
// Pass 1: per-chunk partial sums of 16 quantities:
//   q[0]      = sum w
//   q[1..3]   = sum w*p
//   q[4..6]   = sum w*t
//   q[7+3i+j] = sum w*t_i*p_j     (i = true axis, j = pred axis)
// Masked atoms contribute 0 to every sum (all terms carry w).
// NOTE: mask arrives as int32 (harness converts bool -> int), NOT 1-byte.
// true/weights are read exactly once across the whole problem -> nontemporal
// loads so they don't evict pred (re-read in pass 3) from L2/L3.
// ---------------------------------------------------------------------------
__global__ __launch_bounds__(TPB) void wra_partials(
    const float* __restrict__ pred, const float* __restrict__ tru,
    const float* __restrict__ wgt, const int* __restrict__ mask,
    float* __restrict__ partials)
{
    const int blk = blockIdx.x;
    const int b   = blk >> 2;          // / C1
    const int s   = blk & 3;           // % C1
    const int tid = threadIdx.x;

    float acc[NQ];
    #pragma unroll
    for (int k = 0; k < NQ; ++k) acc[k] = 0.f;

    #pragma unroll 2
    for (int it = 0; it < ITERS; ++it) {
        const long base = (long)b * NATOM + (long)s * ABLK1
                        + (long)it * (TPB * APT) + (long)tid * APT;

        const f32x4* p4 = reinterpret_cast<const f32x4*>(pred + base * 3);
        const f32x4* t4 = reinterpret_cast<const f32x4*>(tru  + base * 3);
        f32x4 pA = p4[0], pB = p4[1], pC = p4[2];
        f32x4 tA = __builtin_nontemporal_load(t4 + 0);
        f32x4 tB = __builtin_nontemporal_load(t4 + 1);
        f32x4 tC = __builtin_nontemporal_load(t4 + 2);
        f32x4 wv = __builtin_nontemporal_load(
                       reinterpret_cast<const f32x4*>(wgt + base));
        i32x4 mv = *reinterpret_cast<const i32x4*>(mask + base);

        float P[12] = {pA.x,pA.y,pA.z,pA.w, pB.x,pB.y,pB.z,pB.w, pC.x,pC.y,pC.z,pC.w};
        float T[12] = {tA.x,tA.y,tA.z,tA.w, tB.x,tB.y,tB.z,tB.w, tC.x,tC.y,tC.z,tC.w};
        float W[4]  = {mv.x ? wv.x : 0.f, mv.y ? wv.y : 0.f,
                       mv.z ? wv.z : 0.f, mv.w ? wv.w : 0.f};

        #pragma unroll
        for (int k = 0; k < APT; ++k) {
            float w  = W[k];
            float px = P[3*k], py = P[3*k+1], pz = P[3*k+2];
            float tx = T[3*k], ty = T[3*k+1], tz = T[3*k+2];
            float wtx = w * tx, wty = w * ty, wtz = w * tz;
            acc[0]  += w;
            acc[1]  += w * px;  acc[2]  += w * py;  acc[3]  += w * pz;
            acc[4]  += wtx;     acc[5]  += wty;     acc[6]  += wtz;
            acc[7]  += wtx*px;  acc[8]  += wtx*py;  acc[9]  += wtx*pz;
            acc[10] += wty*px;  acc[11] += wty*py;  acc[12] += wty*pz;
            acc[13] += wtz*px;  acc[14] += wtz*py;  acc[15] += wtz*pz;
        }
    }

    // wave (64-lane) shuffle reduction, then cross-wave via LDS
    #pragma unroll
    for (int off = 32; off > 0; off >>= 1) {
        #pragma unroll
        for (int k = 0; k < NQ; ++k)
            acc[k] += __shfl_down(acc[k], off, 64);
    }
    __shared__ float red[4][NQ];
    const int wave = tid >> 6, lane = tid & 63;
    if (lane == 0) {
        #pragma unroll
        for (int k = 0; k < NQ; ++k) red[wave][k] = acc[k];
    }
    __syncthreads();
    if (tid < NQ)
        partials[blk * NQ + tid] =
            red[0][tid] + red[1][tid] + red[2][tid] + red[3][tid];
}

// ---------------------------------------------------------------------------
// Pass 2: per batch — reduce chunk partials (fp64), form cov, 3x3 SVD via
// Jacobi eigendecomposition of cov^T cov, build the Kabsch rotation with
// reflection fix, write 15 constants: R (9, row-major), pred_centroid (3),
// true_centroid (3).
// ---------------------------------------------------------------------------
__device__ inline void jrot(double M[3][3], double V[3][3], int p, int q) {
    double mpq = M[p][q];
    if (fabs(mpq) < 1e-300) return;
    double theta = (M[q][q] - M[p][p]) / (2.0 * mpq);
    double t = copysign(1.0, theta) / (fabs(theta) + sqrt(theta * theta + 1.0));
    double c = 1.0 / sqrt(t * t + 1.0);
    double s = t * c;
    int r = 3 - p - q;
    double mpp = M[p][p], mqq = M[q][q], mrp = M[r][p], mrq = M[r][q];
    M[p][p] = mpp - t * mpq;
    M[q][q] = mqq + t * mpq;
    M[p][q] = M[q][p] = 0.0;
    double nrp = c * mrp - s * mrq;
    double nrq = s * mrp + c * mrq;
    M[r][p] = M[p][r] = nrp;
    M[r][q] = M[q][r] = nrq;
    #pragma unroll
    for (int i = 0; i < 3; ++i) {
        double vip = V[i][p], viq = V[i][q];
        V[i][p] = c * vip - s * viq;
        V[i][q] = s * vip + c * viq;
    }
}

__global__ __launch_bounds__(64) void wra_solve(
    const float* __restrict__ partials, float* __restrict__ consts)
{
    const int b = blockIdx.x, tid = threadIdx.x;
    __shared__ double q[NQ];
    if (tid < NQ) {
        double sum = 0.0;
        for (int s = 0; s < C1; ++s)
            sum += (double)partials[(b * C1 + s) * NQ + tid];
        q[tid] = sum;
    }
    __syncthreads();
    if (tid != 0) return;

    double wsum = q[0];
    double pc[3], tc[3];
    for (int j = 0; j < 3; ++j) { pc[j] = q[1+j] / wsum; tc[j] = q[4+j] / wsum; }

    // cov[i][j] = sum w*t_i*p_j - wsum * tc_i * pc_j
    double C[3][3];
    for (int i = 0; i < 3; ++i)
        for (int j = 0; j < 3; ++j)
            C[i][j] = q[7 + 3*i + j] - wsum * tc[i] * pc[j];

    // M = C^T C (symmetric PSD); Jacobi eigendecomposition M = V diag(lam) V^T
    double M[3][3];
    for (int i = 0; i < 3; ++i)
        for (int j = 0; j < 3; ++j)
            M[i][j] = C[0][i]*C[0][j] + C[1][i]*C[1][j] + C[2][i]*C[2][j];
    double V[3][3] = {{1,0,0},{0,1,0},{0,0,1}};
    for (int sweep = 0; sweep < 12; ++sweep) {
        double off = M[0][1]*M[0][1] + M[0][2]*M[0][2] + M[1][2]*M[1][2];
        double diag = M[0][0] + M[1][1] + M[2][2];
        if (off <= 1e-28 * diag * diag) break;
        jrot(M, V, 0, 1);
        jrot(M, V, 0, 2);
        jrot(M, V, 1, 2);
    }
    double lam[3] = {M[0][0], M[1][1], M[2][2]};
    int i0 = 0, i1 = 1, i2 = 2, tmp;
    if (lam[i0] < lam[i1]) { tmp = i0; i0 = i1; i1 = tmp; }
    if (lam[i0] < lam[i2]) { tmp = i0; i0 = i2; i2 = tmp; }
    if (lam[i1] < lam[i2]) { tmp = i1; i1 = i2; i2 = tmp; }
    double v0[3] = {V[0][i0], V[1][i0], V[2][i0]};
    double v1[3] = {V[0][i1], V[1][i1], V[2][i1]};
    double v2[3] = {V[0][i2], V[1][i2], V[2][i2]};

    // u0 = C v0 / |C v0|; u1 = orthonormalized C v1
    double u0[3], u1[3];
    for (int i = 0; i < 3; ++i) {
        u0[i] = C[i][0]*v0[0] + C[i][1]*v0[1] + C[i][2]*v0[2];
        u1[i] = C[i][0]*v1[0] + C[i][1]*v1[1] + C[i][2]*v1[2];
    }
    double n0 = sqrt(u0[0]*u0[0] + u0[1]*u0[1] + u0[2]*u0[2]);
    for (int i = 0; i < 3; ++i) u0[i] /= n0;
    double d01 = u1[0]*u0[0] + u1[1]*u0[1] + u1[2]*u0[2];
    for (int i = 0; i < 3; ++i) u1[i] -= d01 * u0[i];
    double n1 = sqrt(u1[0]*u1[0] + u1[1]*u1[1] + u1[2]*u1[2]);
    for (int i = 0; i < 3; ++i) u1[i] /= n1;

    // Reflection fix: third column of U' = sign(det V) * (u0 x u1); this equals
    // U diag(1,1,d) V^T with d = sign(det U det V) exactly (no 1/sigma_min).
    double detV = v0[0]*(v1[1]*v2[2] - v1[2]*v2[1])
                - v0[1]*(v1[0]*v2[2] - v1[2]*v2[0])
                + v0[2]*(v1[0]*v2[1] - v1[1]*v2[0]);
    double sV = (detV >= 0.0) ? 1.0 : -1.0;
    double u2[3] = { sV * (u0[1]*u1[2] - u0[2]*u1[1]),
                     sV * (u0[2]*u1[0] - u0[0]*u1[2]),
                     sV * (u0[0]*u1[1] - u0[1]*u1[0]) };

    float* out = consts + b * 15;
    for (int i = 0; i < 3; ++i)
        for (int j = 0; j < 3; ++j)
            out[3*i + j] = (float)(u0[i]*v0[j] + u1[i]*v1[j] + u2[i]*v2[j]);
    for (int j = 0; j < 3; ++j) { out[9 + j] = (float)pc[j]; out[12 + j] = (float)tc[j]; }
}

// ---------------------------------------------------------------------------
// Pass 3: out[n][j] = sum_i ((mask? pred:0) - pc)[i] * R[i][j] + tc[j]
// Output is never re-read -> nontemporal stores (keep L2/L3 for pred/mask).
// ---------------------------------------------------------------------------
__global__ __launch_bounds__(TPB) void wra_apply(
    const float* __restrict__ pred, const int* __restrict__ mask,
    const float* __restrict__ consts, float* __restrict__ out)
{
    const int blk = blockIdx.x;
    const int b   = blk >> 4;          // / C3
    const int s   = blk & 15;          // % C3
    const int tid = threadIdx.x;

    __shared__ float c[15];
    if (tid < 15) c[tid] = consts[b * 15 + tid];
    __syncthreads();

    const long base = (long)b * NATOM + (long)s * (TPB * APT) + (long)tid * APT;
    const f32x4* p4 = reinterpret_cast<const f32x4*>(pred + base * 3);
    f32x4 pA = p4[0], pB = p4[1], pC = p4[2];
    i32x4 mv = *reinterpret_cast<const i32x4*>(mask + base);

    float P[12] = {pA.x,pA.y,pA.z,pA.w, pB.x,pB.y,pB.z,pB.w, pC.x,pC.y,pC.z,pC.w};
    int Mk[4] = {mv.x, mv.y, mv.z, mv.w};
    float O[12];

    #pragma unroll
    for (int k = 0; k < APT; ++k) {
        float px = (Mk[k] ? P[3*k]   : 0.f) - c[9];
        float py = (Mk[k] ? P[3*k+1] : 0.f) - c[10];
        float pz = (Mk[k] ? P[3*k+2] : 0.f) - c[11];
        O[3*k]   = px * c[0] + py * c[3] + pz * c[6] + c[12];
        O[3*k+1] = px * c[1] + py * c[4] + pz * c[7] + c[13];
        O[3*k+2] = px * c[2] + py * c[5] + pz * c[8] + c[14];
    }
    f32x4* o4 = reinterpret_cast<f32x4*>(out + base * 3);
    f32x4 o0 = {O[0], O[1], O[2],  O[3]};
    f32x4 o1 = {O[4], O[5], O[6],  O[7]};
    f32x4 o2 = {O[8], O[9], O[10], O[11]};
    __builtin_nontemporal_store(o0, o4 + 0);
    __builtin_nontemporal_store(o1, o4 + 1);
    __builtin_nontemporal_store(o2, o4 + 2);
}

extern "C" void kernel_launch(void* const* d_in, const int* in_sizes, int n_in,
                              void* d_out, int out_size, void* d_ws, size_t ws_size,
                              hipStream_t stream) {
    const float* pred = (const float*)d_in[0];
    const float* tru  = (const float*)d_in[1];
    const float* wgt  = (const float*)d_in[2];
    const int*   mask = (const int*)d_in[3];   // bool input -> int32 per harness
    float* out = (float*)d_out;

    float* partials = (float*)d_ws;                       // BATCH*C1*16 floats
    float* consts   = partials + BATCH * C1 * NQ;         // BATCH*15 floats

    hipLaunchKernelGGL(wra_partials, dim3(BATCH * C1), dim3(TPB), 0, stream,
                       pred, tru, wgt, mask, partials);
    hipLaunchKernelGGL(wra_solve, dim3(BATCH), dim3(64), 0, stream,
                       partials, consts);
    hipLaunchKernelGGL(wra_apply, dim3(BATCH * C3), dim3(TPB), 0, stream,
                       pred, mask, consts, out);
}